// Round 9
// baseline (269.321 us; speedup 1.0000x reference)
//
#include <hip/hip_runtime.h>

// GridGNN: 2x GCNConv(64->64) + ReLU, global_mean_pool, Linear(64->3), softmax.
// N=100000 nodes, E=1600000 edges, G=64 graphs, F=64 feats.
// R1: CSR + gather (no fp32 atomics). 2982 -> 454 us.
// R2: 4-B edge records, gemm2 folded past pooling. -> 393 us.
// R3: head folded; gemm+count fused (fusion HURT: atomics lost TLP). -> 332 us.
// R4: atomic-free CSR (LDS radix, 391 buckets); bf16 feature rows. -> 235 us.
// R5: register-W GEMM; scanC folded into partition/pass2. -> 199 us.
// R6: pool rebuilt; dinv prescaled into bf16 rows. -> 177 us.
// R7: own memset folded into k_hist. -> 172 us. (Profile lesson: top-5 fills
//     were the HARNESS's 268MB ws-poison, outside the timed graph.)
// R8: pool fused into gather2 (Z fp32 buffer eliminated: -51MB traffic,
//     -1 dispatch); gcnt computed in k_hist block 1 from sorted batch.

typedef unsigned int u32;

#define NGRAPH 64
#define SCAN_T 256
#define SCAN_E 16
#define SCAN_B 4096
#define NB1 256  // blocks in hist/partition passes
#define GR 32    // rows per gemm tile (100000 % 32 == 0)

// ---- bf16 helpers (RN pack, exact unpack) ----
__device__ __forceinline__ float bflo(u32 v) { return __uint_as_float(v << 16); }
__device__ __forceinline__ float bfhi(u32 v) { return __uint_as_float(v & 0xffff0000u); }
__device__ __forceinline__ u32 packbf(float a, float b) {
    u32 ua = __float_as_uint(a); ua += 0x7fff + ((ua >> 16) & 1);
    u32 ub = __float_as_uint(b); ub += 0x7fff + ((ub >> 16) & 1);
    return (ua >> 16) | ((ub >> 16) << 16);
}

// ---- gemm: Out(bf16) = dinv[r] * (X @ W). Lane c holds W[:,c] in 64 VGPRs. ----
__global__ void k_gemm_reg(const float* __restrict__ X, const float* __restrict__ W,
                           const float* __restrict__ dinv, u32* __restrict__ Out,
                           int nRows) {
    __shared__ float xs[GR][64];
    int tid = threadIdx.x;      // 256
    int lane = tid & 63;        // output column
    int wv = tid >> 6;          // wave 0..3
    float wreg[64];
#pragma unroll
    for (int k = 0; k < 64; ++k) wreg[k] = W[k * 64 + lane];
    for (int t0 = blockIdx.x * GR; t0 < nRows; t0 += gridDim.x * GR) {
        __syncthreads();
        {
            const float4* X4 = (const float4*)(X + (size_t)t0 * 64);
            float4 v0 = X4[tid];
            float4 v1 = X4[tid + 256];
            ((float4*)&xs[0][0])[tid] = v0;
            ((float4*)&xs[0][0])[tid + 256] = v1;
        }
        __syncthreads();
#pragma unroll
        for (int rr = 0; rr < 8; rr += 4) {
            int r = wv * 8 + rr;
            float a0 = 0.f, a1 = 0.f, a2 = 0.f, a3 = 0.f;
#pragma unroll
            for (int k4 = 0; k4 < 16; ++k4) {
                float4 x0 = *(const float4*)&xs[r + 0][k4 * 4];
                float4 x1 = *(const float4*)&xs[r + 1][k4 * 4];
                float4 x2 = *(const float4*)&xs[r + 2][k4 * 4];
                float4 x3 = *(const float4*)&xs[r + 3][k4 * 4];
                a0 = fmaf(x0.x, wreg[k4 * 4 + 0], a0);
                a1 = fmaf(x1.x, wreg[k4 * 4 + 0], a1);
                a2 = fmaf(x2.x, wreg[k4 * 4 + 0], a2);
                a3 = fmaf(x3.x, wreg[k4 * 4 + 0], a3);
                a0 = fmaf(x0.y, wreg[k4 * 4 + 1], a0);
                a1 = fmaf(x1.y, wreg[k4 * 4 + 1], a1);
                a2 = fmaf(x2.y, wreg[k4 * 4 + 1], a2);
                a3 = fmaf(x3.y, wreg[k4 * 4 + 1], a3);
                a0 = fmaf(x0.z, wreg[k4 * 4 + 2], a0);
                a1 = fmaf(x1.z, wreg[k4 * 4 + 2], a1);
                a2 = fmaf(x2.z, wreg[k4 * 4 + 2], a2);
                a3 = fmaf(x3.z, wreg[k4 * 4 + 2], a3);
                a0 = fmaf(x0.w, wreg[k4 * 4 + 3], a0);
                a1 = fmaf(x1.w, wreg[k4 * 4 + 3], a1);
                a2 = fmaf(x2.w, wreg[k4 * 4 + 3], a2);
                a3 = fmaf(x3.w, wreg[k4 * 4 + 3], a3);
            }
            a0 *= dinv[t0 + r + 0];
            a1 *= dinv[t0 + r + 1];
            a2 *= dinv[t0 + r + 2];
            a3 *= dinv[t0 + r + 3];
            float o0 = __shfl_xor(a0, 1);
            float o1 = __shfl_xor(a1, 1);
            float o2 = __shfl_xor(a2, 1);
            float o3 = __shfl_xor(a3, 1);
            if (!(lane & 1)) {
                int h = lane >> 1;
                Out[(size_t)(t0 + r + 0) * 32 + h] = packbf(a0, o0);
                Out[(size_t)(t0 + r + 1) * 32 + h] = packbf(a1, o1);
                Out[(size_t)(t0 + r + 2) * 32 + h] = packbf(a2, o2);
                Out[(size_t)(t0 + r + 3) * 32 + h] = packbf(a3, o3);
            }
        }
    }
}

// ---- pass 1a: per-block LDS histogram over dst>>8 -> histT[bucket*NB1+block];
//      block 0 zeroes gsum; block 1 builds gcnt from sorted batch ----
__global__ void k_hist(const int* __restrict__ dst, int* __restrict__ histT,
                       float* __restrict__ gsum, const int* __restrict__ batch,
                       float* __restrict__ gcnt, int nN, int nE, int NBUCK) {
    __shared__ int h[512];
    int tid = threadIdx.x;
    if (blockIdx.x == 0) {
        for (int i = tid; i < NGRAPH * 64; i += 256) gsum[i] = 0.f;
    }
    if (blockIdx.x == 1) {
        __shared__ int bcnt[NGRAPH];
        if (tid < NGRAPH) bcnt[tid] = 0;
        __syncthreads();
        for (int i = tid; i < nN; i += 256) atomicAdd(&bcnt[batch[i]], 1);
        __syncthreads();
        if (tid < NGRAPH) gcnt[tid] = (float)bcnt[tid];
    }
    for (int k = tid; k < NBUCK; k += 256) h[k] = 0;
    __syncthreads();
    int i = blockIdx.x * 256 + tid, stride = NB1 * 256;
    for (; i < nE; i += stride) atomicAdd(&h[dst[i] >> 8], 1);
    __syncthreads();
    for (int k = tid; k < NBUCK; k += 256) histT[k * NB1 + blockIdx.x] = h[k];
}

// ---- scan stage A ----
__global__ void k_scanA(const int* __restrict__ arr, int* __restrict__ outp,
                        int* __restrict__ bsums, int L) {
    __shared__ int sh[SCAN_T];
    int b = blockIdx.x, tid = threadIdx.x;
    int base = b * SCAN_B + tid * SCAN_E;
    int v[SCAN_E];
    int s = 0;
#pragma unroll
    for (int j = 0; j < SCAN_E; ++j) {
        int idx = base + j;
        int c = (idx < L) ? arr[idx] : 0;
        v[j] = s;
        s += c;
    }
    sh[tid] = s;
    __syncthreads();
    for (int off = 1; off < SCAN_T; off <<= 1) {
        int t = (tid >= off) ? sh[tid - off] : 0;
        __syncthreads();
        sh[tid] += t;
        __syncthreads();
    }
    int excl = (tid == 0) ? 0 : sh[tid - 1];
    if (tid == SCAN_T - 1) bsums[b] = sh[tid];
#pragma unroll
    for (int j = 0; j < SCAN_E; ++j) {
        int idx = base + j;
        if (idx < L) outp[idx] = excl + v[j];
    }
}

// ---- scan stage B (1 block) + head-weight folding on idle lanes ----
__global__ void k_scanB_fold(int* __restrict__ bsums, int nB,
                             const float* __restrict__ W2, const float* __restrict__ b2,
                             const float* __restrict__ Wl, const float* __restrict__ bl,
                             float* __restrict__ Wc, float* __restrict__ bc) {
    int tid = threadIdx.x;
    if (tid == 0) {
        int run = 0;
        for (int i = 0; i < nB; ++i) {
            int t = bsums[i];
            bsums[i] = run;
            run += t;
        }
    } else if (tid >= 64 && tid < 64 + 192) {
        int i = tid - 64;
        int k = i / 3, j = i % 3;
        float acc = 0.f;
#pragma unroll
        for (int c = 0; c < 64; ++c) acc = fmaf(W2[k * 64 + c], Wl[c * 3 + j], acc);
        Wc[k * 3 + j] = acc;
    } else if (tid >= 1 && tid <= 3) {
        int j = tid - 1;
        float acc = bl[j];
#pragma unroll
        for (int c = 0; c < 64; ++c) acc = fmaf(b2[c], Wl[c * 3 + j], acc);
        bc[j] = acc;
    }
}

// ---- pass 1c: partition edges into buckets via LDS cursors ----
__global__ void k_partition(const int* __restrict__ src, const int* __restrict__ dst,
                            const int* __restrict__ scanned, const int* __restrict__ bsums,
                            u32* __restrict__ staged, int nE, int NBUCK) {
    __shared__ int cur[512];
    int tid = threadIdx.x;
    for (int k = tid; k < NBUCK; k += 256) {
        int idx = k * NB1 + blockIdx.x;
        cur[k] = scanned[idx] + bsums[idx >> 12];
    }
    __syncthreads();
    int i = blockIdx.x * 256 + tid, stride = NB1 * 256;
    for (; i < nE; i += stride) {
        int d = dst[i];
        int k = d >> 8;
        int pos = atomicAdd(&cur[k], 1);
        staged[pos] = (u32)src[i] | ((u32)(d & 255) << 20);
    }
}

// ---- pass 2: per-bucket LDS count+scan+place -> esrc, rowptr, dinv ----
__global__ void k_pass2(const u32* __restrict__ staged, const int* __restrict__ scanned,
                        const int* __restrict__ bsums,
                        float* __restrict__ dinv, int* __restrict__ rowptr,
                        int* __restrict__ esrc, int nN, int nE, int NBUCK) {
    __shared__ int cnt[256], cur[256], sh[256];
    int bk = blockIdx.x, tid = threadIdx.x;
    int i0 = bk * NB1;
    int base = scanned[i0] + bsums[i0 >> 12];
    int end = nE;
    if (bk + 1 < NBUCK) {
        int i1 = (bk + 1) * NB1;
        end = scanned[i1] + bsums[i1 >> 12];
    }
    cnt[tid] = 0;
    __syncthreads();
    for (int e = base + tid; e < end; e += 256) atomicAdd(&cnt[staged[e] >> 20], 1);
    __syncthreads();
    int v = cnt[tid];
    sh[tid] = v;
    __syncthreads();
    for (int off = 1; off < 256; off <<= 1) {
        int t = (tid >= off) ? sh[tid - off] : 0;
        __syncthreads();
        sh[tid] += t;
        __syncthreads();
    }
    int excl = sh[tid] - v;
    int node = bk * 256 + tid;
    if (node < nN) {
        rowptr[node] = base + excl;
        dinv[node] = rsqrtf(1.0f + (float)v);
    }
    cur[tid] = excl;
    __syncthreads();
    for (int e = base + tid; e < end; e += 256) {
        u32 r = staged[e];
        int j = r >> 20;
        int pos = atomicAdd(&cur[j], 1);
        esrc[base + pos] = (int)(r & 0xFFFFFu);
    }
    if (bk == 0 && tid == 0) rowptr[nN] = nE;
}

// ---- layer-1 gather: ys1 = dinv * relu(dinv*(sum hs + self) + b) -> bf16 ----
__global__ void k_gather_bf(const int* __restrict__ rowptr, const int* __restrict__ esrc,
                            const uint2* __restrict__ H, const float* __restrict__ dinv,
                            const float* __restrict__ bias, uint2* __restrict__ Obf,
                            int nN) {
    int node = blockIdx.x * 16 + (threadIdx.x >> 4);
    int lane = threadIdx.x & 15;
    if (node >= nN) return;
    int e0 = rowptr[node], e1 = rowptr[node + 1];
    float4 acc = make_float4(0.f, 0.f, 0.f, 0.f);
#define GSTEP(s) { uint2 v = H[(size_t)(s) * 16 + lane]; \
        acc.x += bflo(v.x); acc.y += bfhi(v.x); \
        acc.z += bflo(v.y); acc.w += bfhi(v.y); }
    int e = e0;
    for (; e + 3 < e1; e += 4) {
        int s0 = esrc[e], s1 = esrc[e + 1], s2 = esrc[e + 2], s3 = esrc[e + 3];
        GSTEP(s0) GSTEP(s1) GSTEP(s2) GSTEP(s3)
    }
    for (; e < e1; ++e) { int s = esrc[e]; GSTEP(s) }
#undef GSTEP
    float di = dinv[node];
    uint2 hv = H[(size_t)node * 16 + lane];
    float4 bb = ((const float4*)bias)[lane];
    float x0 = di * (acc.x + bflo(hv.x)) + bb.x;
    float x1 = di * (acc.y + bfhi(hv.x)) + bb.y;
    float x2 = di * (acc.z + bflo(hv.y)) + bb.z;
    float x3 = di * (acc.w + bfhi(hv.y)) + bb.w;
    x0 = fmaxf(x0, 0.f); x1 = fmaxf(x1, 0.f);
    x2 = fmaxf(x2, 0.f); x3 = fmaxf(x3, 0.f);
    Obf[(size_t)node * 16 + lane] =
        make_uint2(packbf(di * x0, di * x1), packbf(di * x2, di * x3));
}

// ---- layer-2 gather fused with pooling: z never hits memory ----
// z[d] = dinv[d]*(sum ys1[s] + ys1[d]);  gsum[batch[d]] += z[d]
__global__ void k_gather_pool(const int* __restrict__ rowptr, const int* __restrict__ esrc,
                              const uint2* __restrict__ H, const float* __restrict__ dinv,
                              const int* __restrict__ batch, float* __restrict__ gsum,
                              int nN) {
    __shared__ int gsh[16];
    __shared__ float red[4][16][4];
    int tid = threadIdx.x;
    int nodeL = tid >> 4;
    int lane = tid & 15;
    int node = blockIdx.x * 16 + nodeL;
    bool valid = node < nN;
    float4 z = make_float4(0.f, 0.f, 0.f, 0.f);
    int g = 0;
    if (valid) {
        g = batch[node];
        int e0 = rowptr[node], e1 = rowptr[node + 1];
        float4 acc = make_float4(0.f, 0.f, 0.f, 0.f);
#define GSTEP(s) { uint2 v = H[(size_t)(s) * 16 + lane]; \
        acc.x += bflo(v.x); acc.y += bfhi(v.x); \
        acc.z += bflo(v.y); acc.w += bfhi(v.y); }
        int e = e0;
        for (; e + 3 < e1; e += 4) {
            int s0 = esrc[e], s1 = esrc[e + 1], s2 = esrc[e + 2], s3 = esrc[e + 3];
            GSTEP(s0) GSTEP(s1) GSTEP(s2) GSTEP(s3)
        }
        for (; e < e1; ++e) { int s = esrc[e]; GSTEP(s) }
#undef GSTEP
        float di = dinv[node];
        uint2 hv = H[(size_t)node * 16 + lane];
        z.x = di * (acc.x + bflo(hv.x));
        z.y = di * (acc.y + bfhi(hv.x));
        z.z = di * (acc.z + bflo(hv.y));
        z.w = di * (acc.w + bfhi(hv.y));
    }
    if (lane == 0) gsh[nodeL] = valid ? g : -1;
    __syncthreads();
    bool uniform = (gsh[0] == gsh[15]);
    if (uniform) {
        // reduce over the wave's 4 node-slots (lanes differ by 16/32)
        z.x += __shfl_xor(z.x, 16); z.y += __shfl_xor(z.y, 16);
        z.z += __shfl_xor(z.z, 16); z.w += __shfl_xor(z.w, 16);
        z.x += __shfl_xor(z.x, 32); z.y += __shfl_xor(z.y, 32);
        z.z += __shfl_xor(z.z, 32); z.w += __shfl_xor(z.w, 32);
        int wv = tid >> 6, s = tid & 63;
        if (s < 16) {
            red[wv][s][0] = z.x; red[wv][s][1] = z.y;
            red[wv][s][2] = z.z; red[wv][s][3] = z.w;
        }
        __syncthreads();
        if (tid < 16) {
            float t0 = red[0][tid][0] + red[1][tid][0] + red[2][tid][0] + red[3][tid][0];
            float t1 = red[0][tid][1] + red[1][tid][1] + red[2][tid][1] + red[3][tid][1];
            float t2 = red[0][tid][2] + red[1][tid][2] + red[2][tid][2] + red[3][tid][2];
            float t3 = red[0][tid][3] + red[1][tid][3] + red[2][tid][3] + red[3][tid][3];
            float* p = gsum + gsh[0] * 64 + tid * 4;
            unsafeAtomicAdd(p + 0, t0);
            unsafeAtomicAdd(p + 1, t1);
            unsafeAtomicAdd(p + 2, t2);
            unsafeAtomicAdd(p + 3, t3);
        }
    } else if (valid) {
        float* p = gsum + g * 64 + lane * 4;
        unsafeAtomicAdd(p + 0, z.x);
        unsafeAtomicAdd(p + 1, z.y);
        unsafeAtomicAdd(p + 2, z.z);
        unsafeAtomicAdd(p + 3, z.w);
    }
}

// ---- head: out[g] = softmax( mean_g @ Wc + bc ), Wc [64x3] ----
__global__ void k_head(const float* __restrict__ gsum, const float* __restrict__ gcnt,
                       const float* __restrict__ Wc, const float* __restrict__ bc,
                       float* __restrict__ out) {
    int g = threadIdx.x;
    if (g >= NGRAPH) return;
    float inv = 1.0f / fmaxf(gcnt[g], 1.0f);
    float l0 = bc[0], l1 = bc[1], l2 = bc[2];
#pragma unroll
    for (int k = 0; k < 64; ++k) {
        float m = gsum[g * 64 + k] * inv;
        l0 = fmaf(m, Wc[k * 3 + 0], l0);
        l1 = fmaf(m, Wc[k * 3 + 1], l1);
        l2 = fmaf(m, Wc[k * 3 + 2], l2);
    }
    float mx = fmaxf(l0, fmaxf(l1, l2));
    float e0 = expf(l0 - mx), e1 = expf(l1 - mx), e2 = expf(l2 - mx);
    float s = e0 + e1 + e2;
    out[g * 3 + 0] = e0 / s;
    out[g * 3 + 1] = e1 / s;
    out[g * 3 + 2] = e2 / s;
}

extern "C" void kernel_launch(void* const* d_in, const int* in_sizes, int n_in,
                              void* d_out, int out_size, void* d_ws, size_t ws_size,
                              hipStream_t stream) {
    const float* x     = (const float*)d_in[0];
    const int*   ei    = (const int*)d_in[1];
    const int*   batch = (const int*)d_in[2];
    const float* W1    = (const float*)d_in[3];
    const float* b1    = (const float*)d_in[4];
    const float* W2    = (const float*)d_in[5];
    const float* b2    = (const float*)d_in[6];
    const float* Wl    = (const float*)d_in[7];
    const float* bl    = (const float*)d_in[8];
    float* out = (float*)d_out;

    int nN = in_sizes[2];
    int nE = in_sizes[1] / 2;
    const int* srcp = ei;
    const int* dstp = ei + nE;

    int NBUCK = (nN + 255) >> 8;          // 391
    int L = NBUCK * NB1;                   // 100096
    int nB = (L + SCAN_B - 1) / SCAN_B;    // 25

    char* ws = (char*)d_ws;
    size_t off = 0;
    auto alloc = [&](size_t bytes) -> void* {
        void* p = ws + off;
        off += (bytes + 255) & ~(size_t)255;
        return p;
    };
    float* dinv    = (float*)alloc((size_t)nN * 4);
    int*   rowptr  = (int*)alloc(((size_t)nN + 1) * 4);
    int*   hist    = (int*)alloc((size_t)L * 4);
    int*   scanned = (int*)alloc((size_t)L * 4);
    int*   bsums   = (int*)alloc(256 * 4);
    u32*   staged  = (u32*)alloc((size_t)nE * 4);
    int*   esrc    = (int*)alloc((size_t)nE * 4);
    u32*   Hbf     = (u32*)alloc((size_t)nN * 32 * 4);   // bf16-packed [nN][64]
    u32*   Ybf     = (u32*)alloc((size_t)nN * 32 * 4);
    float* gsum    = (float*)alloc(NGRAPH * 64 * 4);
    float* gcnt    = (float*)alloc(NGRAPH * 4);
    float* Wc      = (float*)alloc(64 * 3 * 4);
    float* bc      = (float*)alloc(3 * 4);

    // atomic-free CSR (block0 zeroes gsum, block1 builds gcnt from batch)
    k_hist<<<NB1, 256, 0, stream>>>(dstp, hist, gsum, batch, gcnt, nN, nE, NBUCK);
    k_scanA<<<nB, SCAN_T, 0, stream>>>(hist, scanned, bsums, L);
    k_scanB_fold<<<1, 256, 0, stream>>>(bsums, nB, W2, b2, Wl, bl, Wc, bc);
    k_partition<<<NB1, 256, 0, stream>>>(srcp, dstp, scanned, bsums, staged, nE, NBUCK);
    k_pass2<<<NBUCK, 256, 0, stream>>>(staged, scanned, bsums, dinv, rowptr, esrc, nN, nE, NBUCK);

    // hs = dinv * (x@W1), bf16 rows
    k_gemm_reg<<<1024, 256, 0, stream>>>(x, W1, dinv, Hbf, nN);

    // layer 1: ys1 = dinv * relu(gather(hs)+b1) -> Ybf (bf16)
    k_gather_bf<<<(nN + 15) / 16, 256, 0, stream>>>(
        rowptr, esrc, (const uint2*)Hbf, dinv, b1, (uint2*)Ybf, nN);
    // layer 2 + pool fused: gsum[g] += dinv*(gather(ys1)+self)
    k_gather_pool<<<(nN + 15) / 16, 256, 0, stream>>>(
        rowptr, esrc, (const uint2*)Ybf, dinv, batch, gsum, nN);

    // folded head
    k_head<<<1, 64, 0, stream>>>(gsum, gcnt, Wc, bc, out);
}

// Round 10
// 190.529 us; speedup vs baseline: 1.4135x; 1.4135x over previous
//
#include <hip/hip_runtime.h>

// GridGNN: 2x GCNConv(64->64) + ReLU, global_mean_pool, Linear(64->3), softmax.
// N=100000 nodes, E=1600000 edges, G=64 graphs, F=64 feats.
// R1: CSR + gather (no fp32 atomics). 2982 -> 454 us.
// R2: 4-B edge records, gemm2 folded past pooling. -> 393 us.
// R3: head folded; gemm+count fused (fusion HURT: atomics lost TLP). -> 332 us.
// R4: atomic-free CSR (LDS radix, 391 buckets); bf16 feature rows. -> 235 us.
// R5: register-W GEMM; scanC folded into partition/pass2. -> 199 us.
// R6: pool rebuilt; dinv prescaled into bf16 rows. -> 177 us.
// R7: own memset folded into k_hist. -> 172 us.
// R8: pool fused into gather2; gcnt via k_hist block-1 LDS atomics -> 269 us
//     REGRESSION: sorted batch => all 256 threads same-address LDS atomic,
//     one serialized block gated the whole dispatch (occupancy 0.6%).
// R9: gcnt via 64 binary searches on sorted batch, on idle lanes of
//     k_scanB_fold (512 threads); k_hist reverted to R7 form.

typedef unsigned int u32;

#define NGRAPH 64
#define SCAN_T 256
#define SCAN_E 16
#define SCAN_B 4096
#define NB1 256  // blocks in hist/partition passes
#define GR 32    // rows per gemm tile (100000 % 32 == 0)

// ---- bf16 helpers (RN pack, exact unpack) ----
__device__ __forceinline__ float bflo(u32 v) { return __uint_as_float(v << 16); }
__device__ __forceinline__ float bfhi(u32 v) { return __uint_as_float(v & 0xffff0000u); }
__device__ __forceinline__ u32 packbf(float a, float b) {
    u32 ua = __float_as_uint(a); ua += 0x7fff + ((ua >> 16) & 1);
    u32 ub = __float_as_uint(b); ub += 0x7fff + ((ub >> 16) & 1);
    return (ua >> 16) | ((ub >> 16) << 16);
}

// ---- gemm: Out(bf16) = dinv[r] * (X @ W). Lane c holds W[:,c] in 64 VGPRs. ----
__global__ void k_gemm_reg(const float* __restrict__ X, const float* __restrict__ W,
                           const float* __restrict__ dinv, u32* __restrict__ Out,
                           int nRows) {
    __shared__ float xs[GR][64];
    int tid = threadIdx.x;      // 256
    int lane = tid & 63;        // output column
    int wv = tid >> 6;          // wave 0..3
    float wreg[64];
#pragma unroll
    for (int k = 0; k < 64; ++k) wreg[k] = W[k * 64 + lane];
    for (int t0 = blockIdx.x * GR; t0 < nRows; t0 += gridDim.x * GR) {
        __syncthreads();
        {
            const float4* X4 = (const float4*)(X + (size_t)t0 * 64);
            float4 v0 = X4[tid];
            float4 v1 = X4[tid + 256];
            ((float4*)&xs[0][0])[tid] = v0;
            ((float4*)&xs[0][0])[tid + 256] = v1;
        }
        __syncthreads();
#pragma unroll
        for (int rr = 0; rr < 8; rr += 4) {
            int r = wv * 8 + rr;
            float a0 = 0.f, a1 = 0.f, a2 = 0.f, a3 = 0.f;
#pragma unroll
            for (int k4 = 0; k4 < 16; ++k4) {
                float4 x0 = *(const float4*)&xs[r + 0][k4 * 4];
                float4 x1 = *(const float4*)&xs[r + 1][k4 * 4];
                float4 x2 = *(const float4*)&xs[r + 2][k4 * 4];
                float4 x3 = *(const float4*)&xs[r + 3][k4 * 4];
                a0 = fmaf(x0.x, wreg[k4 * 4 + 0], a0);
                a1 = fmaf(x1.x, wreg[k4 * 4 + 0], a1);
                a2 = fmaf(x2.x, wreg[k4 * 4 + 0], a2);
                a3 = fmaf(x3.x, wreg[k4 * 4 + 0], a3);
                a0 = fmaf(x0.y, wreg[k4 * 4 + 1], a0);
                a1 = fmaf(x1.y, wreg[k4 * 4 + 1], a1);
                a2 = fmaf(x2.y, wreg[k4 * 4 + 1], a2);
                a3 = fmaf(x3.y, wreg[k4 * 4 + 1], a3);
                a0 = fmaf(x0.z, wreg[k4 * 4 + 2], a0);
                a1 = fmaf(x1.z, wreg[k4 * 4 + 2], a1);
                a2 = fmaf(x2.z, wreg[k4 * 4 + 2], a2);
                a3 = fmaf(x3.z, wreg[k4 * 4 + 2], a3);
                a0 = fmaf(x0.w, wreg[k4 * 4 + 3], a0);
                a1 = fmaf(x1.w, wreg[k4 * 4 + 3], a1);
                a2 = fmaf(x2.w, wreg[k4 * 4 + 3], a2);
                a3 = fmaf(x3.w, wreg[k4 * 4 + 3], a3);
            }
            a0 *= dinv[t0 + r + 0];
            a1 *= dinv[t0 + r + 1];
            a2 *= dinv[t0 + r + 2];
            a3 *= dinv[t0 + r + 3];
            float o0 = __shfl_xor(a0, 1);
            float o1 = __shfl_xor(a1, 1);
            float o2 = __shfl_xor(a2, 1);
            float o3 = __shfl_xor(a3, 1);
            if (!(lane & 1)) {
                int h = lane >> 1;
                Out[(size_t)(t0 + r + 0) * 32 + h] = packbf(a0, o0);
                Out[(size_t)(t0 + r + 1) * 32 + h] = packbf(a1, o1);
                Out[(size_t)(t0 + r + 2) * 32 + h] = packbf(a2, o2);
                Out[(size_t)(t0 + r + 3) * 32 + h] = packbf(a3, o3);
            }
        }
    }
}

// ---- pass 1a: per-block LDS histogram over dst>>8 -> histT[bucket*NB1+block];
//      block 0 additionally zeroes gsum ----
__global__ void k_hist(const int* __restrict__ dst, int* __restrict__ histT,
                       float* __restrict__ zbuf, int nZ, int nE, int NBUCK) {
    __shared__ int h[512];
    int tid = threadIdx.x;
    if (blockIdx.x == 0) {
        for (int i = tid; i < nZ; i += 256) zbuf[i] = 0.f;
    }
    for (int k = tid; k < NBUCK; k += 256) h[k] = 0;
    __syncthreads();
    int i = blockIdx.x * 256 + tid, stride = NB1 * 256;
    for (; i < nE; i += stride) atomicAdd(&h[dst[i] >> 8], 1);
    __syncthreads();
    for (int k = tid; k < NBUCK; k += 256) histT[k * NB1 + blockIdx.x] = h[k];
}

// ---- scan stage A ----
__global__ void k_scanA(const int* __restrict__ arr, int* __restrict__ outp,
                        int* __restrict__ bsums, int L) {
    __shared__ int sh[SCAN_T];
    int b = blockIdx.x, tid = threadIdx.x;
    int base = b * SCAN_B + tid * SCAN_E;
    int v[SCAN_E];
    int s = 0;
#pragma unroll
    for (int j = 0; j < SCAN_E; ++j) {
        int idx = base + j;
        int c = (idx < L) ? arr[idx] : 0;
        v[j] = s;
        s += c;
    }
    sh[tid] = s;
    __syncthreads();
    for (int off = 1; off < SCAN_T; off <<= 1) {
        int t = (tid >= off) ? sh[tid - off] : 0;
        __syncthreads();
        sh[tid] += t;
        __syncthreads();
    }
    int excl = (tid == 0) ? 0 : sh[tid - 1];
    if (tid == SCAN_T - 1) bsums[b] = sh[tid];
#pragma unroll
    for (int j = 0; j < SCAN_E; ++j) {
        int idx = base + j;
        if (idx < L) outp[idx] = excl + v[j];
    }
}

// ---- scan stage B (1 block, 512 thr): t0 serial scan; t1-3 bc fold;
//      t64-255 Wc fold; t256-319 gcnt via binary search on sorted batch ----
__global__ void k_scanB_fold(int* __restrict__ bsums, int nB,
                             const float* __restrict__ W2, const float* __restrict__ b2,
                             const float* __restrict__ Wl, const float* __restrict__ bl,
                             float* __restrict__ Wc, float* __restrict__ bc,
                             const int* __restrict__ batch, float* __restrict__ gcnt,
                             int nN) {
    int tid = threadIdx.x;
    if (tid == 0) {
        int run = 0;
        for (int i = 0; i < nB; ++i) {
            int t = bsums[i];
            bsums[i] = run;
            run += t;
        }
    } else if (tid >= 64 && tid < 64 + 192) {
        int i = tid - 64;
        int k = i / 3, j = i % 3;
        float acc = 0.f;
#pragma unroll
        for (int c = 0; c < 64; ++c) acc = fmaf(W2[k * 64 + c], Wl[c * 3 + j], acc);
        Wc[k * 3 + j] = acc;
    } else if (tid >= 1 && tid <= 3) {
        int j = tid - 1;
        float acc = bl[j];
#pragma unroll
        for (int c = 0; c < 64; ++c) acc = fmaf(b2[c], Wl[c * 3 + j], acc);
        bc[j] = acc;
    } else if (tid >= 256 && tid < 256 + NGRAPH) {
        int g = tid - 256;
        // lower_bound(batch, g) and lower_bound(batch, g+1)
        int lo = 0, hi = nN;
        while (lo < hi) { int mid = (lo + hi) >> 1; if (batch[mid] < g) lo = mid + 1; else hi = mid; }
        int lb = lo;
        lo = 0; hi = nN;
        int g1 = g + 1;
        while (lo < hi) { int mid = (lo + hi) >> 1; if (batch[mid] < g1) lo = mid + 1; else hi = mid; }
        gcnt[g] = (float)(lo - lb);
    }
}

// ---- pass 1c: partition edges into buckets via LDS cursors ----
__global__ void k_partition(const int* __restrict__ src, const int* __restrict__ dst,
                            const int* __restrict__ scanned, const int* __restrict__ bsums,
                            u32* __restrict__ staged, int nE, int NBUCK) {
    __shared__ int cur[512];
    int tid = threadIdx.x;
    for (int k = tid; k < NBUCK; k += 256) {
        int idx = k * NB1 + blockIdx.x;
        cur[k] = scanned[idx] + bsums[idx >> 12];
    }
    __syncthreads();
    int i = blockIdx.x * 256 + tid, stride = NB1 * 256;
    for (; i < nE; i += stride) {
        int d = dst[i];
        int k = d >> 8;
        int pos = atomicAdd(&cur[k], 1);
        staged[pos] = (u32)src[i] | ((u32)(d & 255) << 20);
    }
}

// ---- pass 2: per-bucket LDS count+scan+place -> esrc, rowptr, dinv ----
__global__ void k_pass2(const u32* __restrict__ staged, const int* __restrict__ scanned,
                        const int* __restrict__ bsums,
                        float* __restrict__ dinv, int* __restrict__ rowptr,
                        int* __restrict__ esrc, int nN, int nE, int NBUCK) {
    __shared__ int cnt[256], cur[256], sh[256];
    int bk = blockIdx.x, tid = threadIdx.x;
    int i0 = bk * NB1;
    int base = scanned[i0] + bsums[i0 >> 12];
    int end = nE;
    if (bk + 1 < NBUCK) {
        int i1 = (bk + 1) * NB1;
        end = scanned[i1] + bsums[i1 >> 12];
    }
    cnt[tid] = 0;
    __syncthreads();
    for (int e = base + tid; e < end; e += 256) atomicAdd(&cnt[staged[e] >> 20], 1);
    __syncthreads();
    int v = cnt[tid];
    sh[tid] = v;
    __syncthreads();
    for (int off = 1; off < 256; off <<= 1) {
        int t = (tid >= off) ? sh[tid - off] : 0;
        __syncthreads();
        sh[tid] += t;
        __syncthreads();
    }
    int excl = sh[tid] - v;
    int node = bk * 256 + tid;
    if (node < nN) {
        rowptr[node] = base + excl;
        dinv[node] = rsqrtf(1.0f + (float)v);
    }
    cur[tid] = excl;
    __syncthreads();
    for (int e = base + tid; e < end; e += 256) {
        u32 r = staged[e];
        int j = r >> 20;
        int pos = atomicAdd(&cur[j], 1);
        esrc[base + pos] = (int)(r & 0xFFFFFu);
    }
    if (bk == 0 && tid == 0) rowptr[nN] = nE;
}

// ---- layer-1 gather: ys1 = dinv * relu(dinv*(sum hs + self) + b) -> bf16 ----
__global__ void k_gather_bf(const int* __restrict__ rowptr, const int* __restrict__ esrc,
                            const uint2* __restrict__ H, const float* __restrict__ dinv,
                            const float* __restrict__ bias, uint2* __restrict__ Obf,
                            int nN) {
    int node = blockIdx.x * 16 + (threadIdx.x >> 4);
    int lane = threadIdx.x & 15;
    if (node >= nN) return;
    int e0 = rowptr[node], e1 = rowptr[node + 1];
    float4 acc = make_float4(0.f, 0.f, 0.f, 0.f);
#define GSTEP(s) { uint2 v = H[(size_t)(s) * 16 + lane]; \
        acc.x += bflo(v.x); acc.y += bfhi(v.x); \
        acc.z += bflo(v.y); acc.w += bfhi(v.y); }
    int e = e0;
    for (; e + 3 < e1; e += 4) {
        int s0 = esrc[e], s1 = esrc[e + 1], s2 = esrc[e + 2], s3 = esrc[e + 3];
        GSTEP(s0) GSTEP(s1) GSTEP(s2) GSTEP(s3)
    }
    for (; e < e1; ++e) { int s = esrc[e]; GSTEP(s) }
#undef GSTEP
    float di = dinv[node];
    uint2 hv = H[(size_t)node * 16 + lane];
    float4 bb = ((const float4*)bias)[lane];
    float x0 = di * (acc.x + bflo(hv.x)) + bb.x;
    float x1 = di * (acc.y + bfhi(hv.x)) + bb.y;
    float x2 = di * (acc.z + bflo(hv.y)) + bb.z;
    float x3 = di * (acc.w + bfhi(hv.y)) + bb.w;
    x0 = fmaxf(x0, 0.f); x1 = fmaxf(x1, 0.f);
    x2 = fmaxf(x2, 0.f); x3 = fmaxf(x3, 0.f);
    Obf[(size_t)node * 16 + lane] =
        make_uint2(packbf(di * x0, di * x1), packbf(di * x2, di * x3));
}

// ---- layer-2 gather fused with pooling: z never hits memory ----
__global__ void k_gather_pool(const int* __restrict__ rowptr, const int* __restrict__ esrc,
                              const uint2* __restrict__ H, const float* __restrict__ dinv,
                              const int* __restrict__ batch, float* __restrict__ gsum,
                              int nN) {
    __shared__ int gsh[16];
    __shared__ float red[4][16][4];
    int tid = threadIdx.x;
    int nodeL = tid >> 4;
    int lane = tid & 15;
    int node = blockIdx.x * 16 + nodeL;
    bool valid = node < nN;
    float4 z = make_float4(0.f, 0.f, 0.f, 0.f);
    int g = 0;
    if (valid) {
        g = batch[node];
        int e0 = rowptr[node], e1 = rowptr[node + 1];
        float4 acc = make_float4(0.f, 0.f, 0.f, 0.f);
#define GSTEP(s) { uint2 v = H[(size_t)(s) * 16 + lane]; \
        acc.x += bflo(v.x); acc.y += bfhi(v.x); \
        acc.z += bflo(v.y); acc.w += bfhi(v.y); }
        int e = e0;
        for (; e + 3 < e1; e += 4) {
            int s0 = esrc[e], s1 = esrc[e + 1], s2 = esrc[e + 2], s3 = esrc[e + 3];
            GSTEP(s0) GSTEP(s1) GSTEP(s2) GSTEP(s3)
        }
        for (; e < e1; ++e) { int s = esrc[e]; GSTEP(s) }
#undef GSTEP
        float di = dinv[node];
        uint2 hv = H[(size_t)node * 16 + lane];
        z.x = di * (acc.x + bflo(hv.x));
        z.y = di * (acc.y + bfhi(hv.x));
        z.z = di * (acc.z + bflo(hv.y));
        z.w = di * (acc.w + bfhi(hv.y));
    }
    if (lane == 0) gsh[nodeL] = valid ? g : -1;
    __syncthreads();
    bool uniform = (gsh[0] == gsh[15]);
    if (uniform) {
        z.x += __shfl_xor(z.x, 16); z.y += __shfl_xor(z.y, 16);
        z.z += __shfl_xor(z.z, 16); z.w += __shfl_xor(z.w, 16);
        z.x += __shfl_xor(z.x, 32); z.y += __shfl_xor(z.y, 32);
        z.z += __shfl_xor(z.z, 32); z.w += __shfl_xor(z.w, 32);
        int wv = tid >> 6, s = tid & 63;
        if (s < 16) {
            red[wv][s][0] = z.x; red[wv][s][1] = z.y;
            red[wv][s][2] = z.z; red[wv][s][3] = z.w;
        }
        __syncthreads();
        if (tid < 16) {
            float t0 = red[0][tid][0] + red[1][tid][0] + red[2][tid][0] + red[3][tid][0];
            float t1 = red[0][tid][1] + red[1][tid][1] + red[2][tid][1] + red[3][tid][1];
            float t2 = red[0][tid][2] + red[1][tid][2] + red[2][tid][2] + red[3][tid][2];
            float t3 = red[0][tid][3] + red[1][tid][3] + red[2][tid][3] + red[3][tid][3];
            float* p = gsum + gsh[0] * 64 + tid * 4;
            unsafeAtomicAdd(p + 0, t0);
            unsafeAtomicAdd(p + 1, t1);
            unsafeAtomicAdd(p + 2, t2);
            unsafeAtomicAdd(p + 3, t3);
        }
    } else if (valid) {
        float* p = gsum + g * 64 + lane * 4;
        unsafeAtomicAdd(p + 0, z.x);
        unsafeAtomicAdd(p + 1, z.y);
        unsafeAtomicAdd(p + 2, z.z);
        unsafeAtomicAdd(p + 3, z.w);
    }
}

// ---- head: out[g] = softmax( mean_g @ Wc + bc ), Wc [64x3] ----
__global__ void k_head(const float* __restrict__ gsum, const float* __restrict__ gcnt,
                       const float* __restrict__ Wc, const float* __restrict__ bc,
                       float* __restrict__ out) {
    int g = threadIdx.x;
    if (g >= NGRAPH) return;
    float inv = 1.0f / fmaxf(gcnt[g], 1.0f);
    float l0 = bc[0], l1 = bc[1], l2 = bc[2];
#pragma unroll
    for (int k = 0; k < 64; ++k) {
        float m = gsum[g * 64 + k] * inv;
        l0 = fmaf(m, Wc[k * 3 + 0], l0);
        l1 = fmaf(m, Wc[k * 3 + 1], l1);
        l2 = fmaf(m, Wc[k * 3 + 2], l2);
    }
    float mx = fmaxf(l0, fmaxf(l1, l2));
    float e0 = expf(l0 - mx), e1 = expf(l1 - mx), e2 = expf(l2 - mx);
    float s = e0 + e1 + e2;
    out[g * 3 + 0] = e0 / s;
    out[g * 3 + 1] = e1 / s;
    out[g * 3 + 2] = e2 / s;
}

extern "C" void kernel_launch(void* const* d_in, const int* in_sizes, int n_in,
                              void* d_out, int out_size, void* d_ws, size_t ws_size,
                              hipStream_t stream) {
    const float* x     = (const float*)d_in[0];
    const int*   ei    = (const int*)d_in[1];
    const int*   batch = (const int*)d_in[2];
    const float* W1    = (const float*)d_in[3];
    const float* b1    = (const float*)d_in[4];
    const float* W2    = (const float*)d_in[5];
    const float* b2    = (const float*)d_in[6];
    const float* Wl    = (const float*)d_in[7];
    const float* bl    = (const float*)d_in[8];
    float* out = (float*)d_out;

    int nN = in_sizes[2];
    int nE = in_sizes[1] / 2;
    const int* srcp = ei;
    const int* dstp = ei + nE;

    int NBUCK = (nN + 255) >> 8;          // 391
    int L = NBUCK * NB1;                   // 100096
    int nB = (L + SCAN_B - 1) / SCAN_B;    // 25

    char* ws = (char*)d_ws;
    size_t off = 0;
    auto alloc = [&](size_t bytes) -> void* {
        void* p = ws + off;
        off += (bytes + 255) & ~(size_t)255;
        return p;
    };
    float* dinv    = (float*)alloc((size_t)nN * 4);
    int*   rowptr  = (int*)alloc(((size_t)nN + 1) * 4);
    int*   hist    = (int*)alloc((size_t)L * 4);
    int*   scanned = (int*)alloc((size_t)L * 4);
    int*   bsums   = (int*)alloc(256 * 4);
    u32*   staged  = (u32*)alloc((size_t)nE * 4);
    int*   esrc    = (int*)alloc((size_t)nE * 4);
    u32*   Hbf     = (u32*)alloc((size_t)nN * 32 * 4);   // bf16-packed [nN][64]
    u32*   Ybf     = (u32*)alloc((size_t)nN * 32 * 4);
    float* gsum    = (float*)alloc(NGRAPH * 64 * 4);
    float* gcnt    = (float*)alloc(NGRAPH * 4);
    float* Wc      = (float*)alloc(64 * 3 * 4);
    float* bc      = (float*)alloc(3 * 4);

    // atomic-free CSR (block 0 zeroes gsum; gcnt set in scanB via bsearch)
    k_hist<<<NB1, 256, 0, stream>>>(dstp, hist, gsum, NGRAPH * 64, nE, NBUCK);
    k_scanA<<<nB, SCAN_T, 0, stream>>>(hist, scanned, bsums, L);
    k_scanB_fold<<<1, 512, 0, stream>>>(bsums, nB, W2, b2, Wl, bl, Wc, bc,
                                        batch, gcnt, nN);
    k_partition<<<NB1, 256, 0, stream>>>(srcp, dstp, scanned, bsums, staged, nE, NBUCK);
    k_pass2<<<NBUCK, 256, 0, stream>>>(staged, scanned, bsums, dinv, rowptr, esrc, nN, nE, NBUCK);

    // hs = dinv * (x@W1), bf16 rows
    k_gemm_reg<<<1024, 256, 0, stream>>>(x, W1, dinv, Hbf, nN);

    // layer 1: ys1 = dinv * relu(gather(hs)+b1) -> Ybf (bf16)
    k_gather_bf<<<(nN + 15) / 16, 256, 0, stream>>>(
        rowptr, esrc, (const uint2*)Hbf, dinv, b1, (uint2*)Ybf, nN);
    // layer 2 + pool fused: gsum[g] += dinv*(gather(ys1)+self)
    k_gather_pool<<<(nN + 15) / 16, 256, 0, stream>>>(
        rowptr, esrc, (const uint2*)Ybf, dinv, batch, gsum, nN);

    // folded head
    k_head<<<1, 64, 0, stream>>>(gsum, gcnt, Wc, bc, out);
}